// Round 16
// baseline (2112.436 us; speedup 1.0000x reference)
//
#include <hip/hip_runtime.h>
#include <hip/hip_bf16.h>

// ---------------------------------------------------------------------------
// InvSlotAttentionGuide: CNN encoder -> pos embed -> MLP -> slot attention
// with MESH-Sinkhorn (manual reverse-mode through 5 sinkhorn iters).
// R16: sa_kernel packs 2 independent batch items per block (8 blocks x 1024
// threads = 16 waves/CU; disjoint LDS halves; waves never straddle items) so
// the ~50% barrier/LDS stall fraction of the two items overlaps (m114-style
// co-scheduling). Per-item arithmetic identical to R13. Conv/token R13-exact.
// ---------------------------------------------------------------------------

#define LN_EPS 1e-5f
#define SEPS 1e-8f
#define LN8 2.0794415416798357f

__device__ inline float ldf(float x) { return x; }
__device__ inline float ldf(__hip_bfloat16 x) { return __bfloat162float(x); }
__device__ inline void stf(float* p, float v) { *p = v; }
__device__ inline void stf(__hip_bfloat16* p, float v) { *p = __float2bfloat16(v); }

__device__ inline float wmaxall(float v) {
#pragma unroll
  for (int o = 32; o; o >>= 1) v = fmaxf(v, __shfl_down(v, o));
  return __shfl(v, 0);
}
__device__ inline float wsumall(float v) {
#pragma unroll
  for (int o = 32; o; o >>= 1) v += __shfl_down(v, o);
  return __shfl(v, 0);
}
__device__ inline int wsumi(int v) {
#pragma unroll
  for (int o = 32; o; o >>= 1) v += __shfl_down(v, o);
  return __shfl(v, 0);
}
__device__ inline float fast_sigmoid(float x) { return 1.f / (1.f + __expf(-x)); }
__device__ inline float fast_tanh(float x) { return 1.f - 2.f / (__expf(2.f * x) + 1.f); }

// ---------------------------------------------------------------------------
__global__ __launch_bounds__(64) void sniff_kernel(const unsigned int* __restrict__ img,
                                                   int* __restrict__ flag) {
  int cnt = 0;
  for (int i = threadIdx.x; i < 512; i += 64) {
    unsigned lo = img[i] & 0xFFFFu;
    int e = (int)((lo >> 7) & 0xFFu);
    cnt += (e >= 96 && e <= 140) ? 1 : 0;
  }
  cnt = wsumi(cnt);
  if (threadIdx.x == 0) *flag = (cnt >= 300) ? 1 : 0;
}

struct CvtArgs {
  const void* src[39];
  long off[40];
};

__global__ __launch_bounds__(256) void convert_kernel(CvtArgs a, const int* __restrict__ flag,
                                                      float* __restrict__ dst, long total) {
  const int isbf = *flag;
  for (long g = (long)blockIdx.x * 256 + threadIdx.x; g < total; g += (long)gridDim.x * 256) {
    int lo = 0, hi = 38;
    while (lo < hi) {
      int mid = (lo + hi + 1) >> 1;
      if (a.off[mid] <= g) lo = mid; else hi = mid - 1;
    }
    long li = g - a.off[lo];
    float v;
    if (isbf) v = __bfloat162float(((const __hip_bfloat16*)a.src[lo])[li]);
    else      v = ((const float*)a.src[lo])[li];
    dst[g] = v;
  }
}

// ---------------------------------------------------------------------------
struct TwArgs {
  long soff[9]; long doff[9]; int R[9]; int C[9];
};

__global__ __launch_bounds__(256) void transw_kernel(const float* __restrict__ cvt,
                                                     float* __restrict__ tws, TwArgs a) {
  int m = blockIdx.x;
  const float* S = cvt + a.soff[m];
  float* D = tws + a.doff[m];
  int R = a.R[m], C = a.C[m];
  for (int idx = threadIdx.x; idx < R * C; idx += 256) {
    int i = idx / C, j = idx - i * C;
    D[j * R + i] = S[idx];
  }
}

// ---------------------------------------------------------------------------
// Direct 5x5 conv + bias + relu (R13-exact): 16x16 tile x 16 oc per block,
// float4 win loads from padded rows, wt[tap][16] broadcast b128.
// ---------------------------------------------------------------------------
template <int S, typename TIN, typename TOUT>
__global__ __launch_bounds__(256) void conv5x5(
    const TIN* __restrict__ in, const float* __restrict__ wgt,
    const float* __restrict__ bias, TOUT* __restrict__ out,
    int Cin, int H, int W, int Ho, int Wo, int Cout, int tilesX) {
  constexpr int P = 15 * S + 5;
  constexpr int PP = (S == 1) ? 20 : 36;
  constexpr int NCH = (S == 1) ? 2 : 3;
  __shared__ __align__(16) float patch[P * PP];
  __shared__ float wt16[25 * 16];
  const int b = blockIdx.z;
  const int ocg = blockIdx.y * 16;
  const int ty0 = (blockIdx.x / tilesX) * 16, tx0 = (blockIdx.x % tilesX) * 16;
  const int og = threadIdx.x >> 6;
  const int r = (threadIdx.x >> 2) & 15;
  const int rx = threadIdx.x & 3;
  const int iy0 = ty0 * S - 2, ix0 = tx0 * S - 2;
  float acc[4][4];
#pragma unroll
  for (int p = 0; p < 4; p++)
#pragma unroll
    for (int j = 0; j < 4; j++) acc[p][j] = 0.f;

  for (int ci = 0; ci < Cin; ++ci) {
    const TIN* inp = in + ((long)b * Cin + ci) * (long)H * W;
    for (int idx = threadIdx.x; idx < P * P; idx += 256) {
      int py = idx / P, px = idx - py * P;
      int iy = iy0 + py, ix = ix0 + px;
      float v = 0.f;
      if (iy >= 0 && iy < H && ix >= 0 && ix < W) v = ldf(inp[(long)iy * W + ix]);
      patch[py * PP + px] = v;
    }
    for (int idx = threadIdx.x; idx < 16 * 25; idx += 256) {
      int tap = idx >> 4, j = idx & 15;
      wt16[idx] = wgt[((long)(ocg + j) * Cin + ci) * 25 + tap];
    }
    __syncthreads();
#pragma unroll
    for (int ky = 0; ky < 5; ky++) {
      float win[4 * NCH];
      const float* bp = &patch[(r * S + ky) * PP + rx * 4 * S];
#pragma unroll
      for (int c = 0; c < NCH; c++) {
        float4 t4 = *(const float4*)(bp + 4 * c);
        win[4 * c + 0] = t4.x;
        win[4 * c + 1] = t4.y;
        win[4 * c + 2] = t4.z;
        win[4 * c + 3] = t4.w;
      }
#pragma unroll
      for (int kx = 0; kx < 5; kx++) {
        const float4 wv = *(const float4*)&wt16[(ky * 5 + kx) * 16 + og * 4];
#pragma unroll
        for (int p = 0; p < 4; p++) {
          float iv = win[p * S + kx];
          acc[p][0] += iv * wv.x;
          acc[p][1] += iv * wv.y;
          acc[p][2] += iv * wv.z;
          acc[p][3] += iv * wv.w;
        }
      }
    }
    __syncthreads();
  }
  const int oy = ty0 + r, ox0 = tx0 + rx * 4;
#pragma unroll
  for (int j = 0; j < 4; j++) {
    int oc = ocg + og * 4 + j;
    float bs = bias[oc];
    TOUT* op = &out[(((long)b * Cout + oc) * Ho + oy) * Wo + ox0];
#pragma unroll
    for (int p = 0; p < 4; p++) stf(&op[p], fmaxf(acc[p][j] + bs, 0.f));
  }
}

// ---------------------------------------------------------------------------
// Per-token (one wave): inline pos-embed from act4 -> MLP -> LN -> k
// (l2norm, stored TRANSPOSED [d][n]), v, mwi logit.  (R13-exact)
// ---------------------------------------------------------------------------
__global__ __launch_bounds__(64) void token_kernel(
    const float* __restrict__ act4, const float* __restrict__ pos_w,
    const float* __restrict__ pos_b,
    const float* __restrict__ mlp1T, const float* __restrict__ mlp1_b,
    const float* __restrict__ mlp2T, const float* __restrict__ mlp2_b,
    const float* __restrict__ lnin_w, const float* __restrict__ lnin_b,
    const float* __restrict__ wkT, const float* __restrict__ wvT,
    const float* __restrict__ mwi_w, const float* __restrict__ mwi_b,
    float* __restrict__ knT_out, float* __restrict__ v_out, float* __restrict__ lg_out) {
  const int t = blockIdx.x, i = threadIdx.x;
  const int b = t >> 10, nn = t & 1023;
  const int h = nn >> 5, w = nn & 31;
  __shared__ float f[64], h1[64], inp[64];
  {
    float gh = h * (1.f / 31.f), gw = w * (1.f / 31.f);
    float e = gh * pos_w[i * 4 + 0] + gw * pos_w[i * 4 + 1] +
              (1.f - gh) * pos_w[i * 4 + 2] + (1.f - gw) * pos_w[i * 4 + 3] + pos_b[i];
    f[i] = act4[(((long)b * 64 + i) * 32 + h) * 32 + w] + e;
  }
  __syncthreads();
  float acc = 0.f;
  for (int j = 0; j < 64; j++) acc += f[j] * mlp1T[j * 64 + i];
  h1[i] = fmaxf(acc + mlp1_b[i], 0.f);
  __syncthreads();
  acc = 0.f;
  for (int j = 0; j < 64; j++) acc += h1[j] * mlp2T[j * 64 + i];
  float x = acc + mlp2_b[i];
  float m = wsumall(x) * (1.f / 64.f);
  float d0 = x - m;
  float var = wsumall(d0 * d0) * (1.f / 64.f);
  float xin = d0 * rsqrtf(var + LN_EPS) * lnin_w[i] + lnin_b[i];
  inp[i] = xin;
  __syncthreads();
  float kv = 0.f, vv = 0.f;
  for (int j = 0; j < 64; j++) {
    float ij = inp[j];
    kv += ij * wkT[j * 64 + i];
    vv += ij * wvT[j * 64 + i];
  }
  float ss = wsumall(kv * kv);
  knT_out[(long)b * 65536 + i * 1024 + nn] = kv / fmaxf(sqrtf(ss), 1e-12f);
  v_out[(long)t * 64 + i] = vv;
  float lg = wsumall(xin * mwi_w[i]);
  if (i == 0) lg_out[t] = lg + mwi_b[0];
}

// ---------------------------------------------------------------------------
// Slot-attention loop: 8 blocks x 1024 threads; each block runs TWO
// independent batch items (item = tid>>9) in disjoint LDS halves. Per-item
// logic is R13-exact (512 threads, 8 waves; waves never straddle items).
// ---------------------------------------------------------------------------
__global__ __launch_bounds__(1024) void sa_kernel(
    const float* __restrict__ knT_g, const float* __restrict__ v_g,
    const float* __restrict__ la_g, const float* __restrict__ noise,
    const float* __restrict__ mu_w, const float* __restrict__ sg_w,
    const float* __restrict__ lnsl_w, const float* __restrict__ lnsl_b,
    const float* __restrict__ mws_w, const float* __restrict__ mws_b,
    const float* __restrict__ wqT,
    const float* __restrict__ wihT, const float* __restrict__ whhT,
    const float* __restrict__ bih, const float* __restrict__ bhh,
    const float* __restrict__ lnff_w, const float* __restrict__ lnff_b,
    const float* __restrict__ fc1T, const float* __restrict__ fc1_b,
    const float* __restrict__ fc2T, const float* __restrict__ fc2_b,
    float* __restrict__ out) {
  const int tid = threadIdx.x;
  const int item = tid >> 9;          // 0 or 1
  const int t2 = tid & 511;           // thread id within item
  const int wv = (tid >> 6) & 7;      // wave within item
  const int ln = tid & 63;
  const int b = blockIdx.x * 2 + item;

  __shared__ float sCt[2][8192];
  __shared__ float sLa[2][1024], sU[2][1024], sGu[2][1024], sRow[2][1024], sHid[2][1024];
  __shared__ float sVh[2][48], sV[2][8], sGv[2][8], sLb[2][8], sBm[2][8];
  __shared__ float sLaMax[2];
  __shared__ float sSlots[2][512], sNorm[2][512], sQn[2][512], sUpd[2][512];

  const float* knt = knT_g + (long)b * 65536;
  const float* vf = v_g + (long)b * 65536;
  float u_hist[5][2];
  float gPr[2][8];
  float gInit[2];

  {
    int dd = t2 & 63;
    sSlots[item][t2] = mu_w[dd] + (fabsf(sg_w[dd]) + SEPS) * noise[(long)b * 512 + t2];
  }
  for (int n = t2; n < 1024; n += 512) sLa[item][n] = la_g[b * 1024 + n];
  __syncthreads();
  {  // fused la: sLa <- raw - LSE + ln8 ; record laMax
    float a0 = sLa[item][t2], a1 = sLa[item][t2 + 512];
    float m0 = wmaxall(fmaxf(a0, a1));
    if (ln == 0) sBm[item][wv] = m0;
    __syncthreads();
    float M = sBm[item][0];
#pragma unroll
    for (int s = 1; s < 8; s++) M = fmaxf(M, sBm[item][s]);
    float e0 = wsumall(__expf(a0 - M) + __expf(a1 - M));
    if (ln == 0) sGv[item][wv] = e0;
    __syncthreads();
    float SS = 0.f;
#pragma unroll
    for (int s = 0; s < 8; s++) SS += sGv[item][s];
    float lse = M + __logf(SS);
    sLa[item][t2] = a0 - lse + LN8;
    sLa[item][t2 + 512] = a1 - lse + LN8;
    if (t2 == 0) sLaMax[item] = M - lse + LN8;
  }
  __syncthreads();
  const float laMax = sLaMax[item];

  for (int it = 0; it < 3; ++it) {
    {
      float x = sSlots[item][wv * 64 + ln];
      float m = wsumall(x) * (1.f / 64.f);
      float d0 = x - m;
      float var = wsumall(d0 * d0) * (1.f / 64.f);
      float xn = d0 * rsqrtf(var + LN_EPS) * lnsl_w[ln] + lnsl_b[ln];
      sNorm[item][wv * 64 + ln] = xn;
      float bmv = wsumall(xn * mws_w[ln]);
      if (ln == 0) sBm[item][wv] = bmv + mws_b[0];
    }
    __syncthreads();
    if (t2 == 0) {
      float mx = -1e30f;
      for (int s = 0; s < 8; s++) mx = fmaxf(mx, sBm[item][s]);
      float ss = 0.f;
      for (int s = 0; s < 8; s++) ss += __expf(sBm[item][s] - mx);
      float lse = mx + __logf(ss);
      for (int s = 0; s < 8; s++) sLb[item][s] = sBm[item][s] - lse + LN8;
    }
    {
      float acc = 0.f;
      for (int j = 0; j < 64; j++) acc += sNorm[item][wv * 64 + j] * wqT[j * 64 + ln];
      sQn[item][t2] = acc;
    }
    __syncthreads();
    {
      float qv = sQn[item][wv * 64 + ln];
      float ss = wsumall(qv * qv);
      sQn[item][wv * 64 + ln] = qv / fmaxf(sqrtf(ss), 1e-12f);
    }
    if (t2 < 8) sV[item][t2] = 0.f;
    __syncthreads();

#pragma unroll
    for (int k = 0; k < 2; k++) {
      int n = t2 + 512 * k;
      float acc[8];
#pragma unroll
      for (int s = 0; s < 8; s++) acc[s] = 0.f;
      for (int j = 0; j < 64; j++) {
        float kvv = knt[j * 1024 + n];
#pragma unroll
        for (int s = 0; s < 8; s++) acc[s] += kvv * sQn[item][s * 64 + j];
      }
#pragma unroll
      for (int s = 0; s < 8; s++) sCt[item][s * 1024 + n] = 1.f - acc[s];
    }
    __syncthreads();

    for (int m = 0; m < 4; m++) {
#pragma unroll
      for (int t = 1; t <= 5; t++) {
        if (t == 1 && t2 < 8) sVh[item][t2] = sV[item][t2];
#pragma unroll
        for (int k = 0; k < 2; k++) {
          int n = t2 + 512 * k;
          float mx = -1e30f;
#pragma unroll
          for (int s = 0; s < 8; s++) mx = fmaxf(mx, sV[item][s] - sCt[item][s * 1024 + n]);
          float ssum = 0.f;
#pragma unroll
          for (int s = 0; s < 8; s++) ssum += __expf(sV[item][s] - sCt[item][s * 1024 + n] - mx);
          float un = sLa[item][n] - (mx + __logf(ssum));
          sU[item][n] = un;
          u_hist[t - 1][k] = un;
        }
        __syncthreads();
        {
          int s = wv;
          float ms = laMax - sV[item][s];
          float ssum = 0.f;
          for (int n = ln; n < 1024; n += 64)
            ssum += __expf(sU[item][n] - sCt[item][s * 1024 + n] - ms);
          ssum = wsumall(ssum);
          if (ln == 0) {
            float vs = sLb[item][s] - (ms + __logf(ssum));
            sV[item][s] = vs;
            sVh[item][t * 8 + s] = vs;
          }
        }
        __syncthreads();
      }
      {
#pragma unroll
        for (int k = 0; k < 2; k++) {
          int n = t2 + 512 * k;
          float un = u_hist[4][k];
          float gul = 0.f;
#pragma unroll
          for (int s = 0; s < 8; s++) {
            float pi = __expf(un + sV[item][s] - sCt[item][s * 1024 + n]);
            float gl = -(__logf(pi + SEPS) + pi / (pi + SEPS)) * pi * (1.f / 16.f);
            gPr[k][s] = gl;
            gul += gl;
          }
          gInit[k] = gul;
        }
        {
          int s = wv;
          float vs = sV[item][s];
          float acc = 0.f;
          for (int n = ln; n < 1024; n += 64) {
            float pi = __expf(sU[item][n] + vs - sCt[item][s * 1024 + n]);
            acc += -(__logf(pi + SEPS) + pi / (pi + SEPS)) * pi * (1.f / 16.f);
          }
          acc = wsumall(acc);
          if (ln == 0) sGv[item][s] = acc;
        }
      }
      __syncthreads();
#pragma unroll
      for (int t = 5; t >= 1; t--) {
        {
#pragma unroll
          for (int k = 0; k < 2; k++) {
            int n = t2 + 512 * k;
            float un = u_hist[t - 1][k];
            float gul = (t == 5) ? gInit[k] : 0.f;
#pragma unroll
            for (int s = 0; s < 8; s++) {
              float t2v = sGv[item][s] *
                          __expf(un - sCt[item][s * 1024 + n] - (sLb[item][s] - sVh[item][t * 8 + s]));
              gPr[k][s] -= t2v;
              gul -= t2v;
            }
            float rowlse = sLa[item][n] - un;
#pragma unroll
            for (int s = 0; s < 8; s++)
              gPr[k][s] -= gul * __expf(sVh[item][(t - 1) * 8 + s] - sCt[item][s * 1024 + n] - rowlse);
            sGu[item][n] = gul;
            sRow[item][n] = rowlse;
            if (t == 1) {
#pragma unroll
              for (int s = 0; s < 8; s++) sCt[item][s * 1024 + n] += gPr[k][s];
            }
          }
          if (t == 1 && t2 < 8) sV[item][t2] = sVh[item][40 + t2];
        }
        __syncthreads();
        if (t > 1) {
          int s = wv;
          float vvh = sVh[item][(t - 1) * 8 + s];
          float acc = 0.f;
          for (int n = ln; n < 1024; n += 64)
            acc += sGu[item][n] * __expf(vvh - sCt[item][s * 1024 + n] - sRow[item][n]);
          acc = wsumall(acc);
          if (ln == 0) sGv[item][s] = -acc;
          __syncthreads();
        }
      }
    }

    for (int t = 0; t < 5; t++) {
#pragma unroll
      for (int k = 0; k < 2; k++) {
        int n = t2 + 512 * k;
        float mx = -1e30f;
#pragma unroll
        for (int s = 0; s < 8; s++) mx = fmaxf(mx, sV[item][s] - sCt[item][s * 1024 + n]);
        float ssum = 0.f;
#pragma unroll
        for (int s = 0; s < 8; s++) ssum += __expf(sV[item][s] - sCt[item][s * 1024 + n] - mx);
        sU[item][n] = sLa[item][n] - (mx + __logf(ssum));
      }
      __syncthreads();
      {
        int s = wv;
        float ms = laMax - sV[item][s];
        float ssum = 0.f;
        for (int n = ln; n < 1024; n += 64)
          ssum += __expf(sU[item][n] - sCt[item][s * 1024 + n] - ms);
        ssum = wsumall(ssum);
        if (ln == 0) sV[item][s] = sLb[item][s] - (ms + __logf(ssum));
      }
      __syncthreads();
    }
#pragma unroll
    for (int k = 0; k < 2; k++) {
      int n = t2 + 512 * k;
      float un = sU[item][n];
#pragma unroll
      for (int s = 0; s < 8; s++)
        sCt[item][s * 1024 + n] = __expf(un + sV[item][s] - sCt[item][s * 1024 + n]);
    }
    __syncthreads();
    if (it == 2) {
      for (int o = t2; o < 8192; o += 512) out[8192 + (long)b * 8192 + o] = sCt[item][o];
    }
    {
      int s = t2 >> 6, dd = t2 & 63;
      float acc = 0.f;
      for (int n = 0; n < 1024; n++) acc += sCt[item][s * 1024 + n] * vf[n * 64 + dd];
      sUpd[item][t2] = acc;
    }
    __syncthreads();
    float newslot;
    {
      int s = t2 >> 6, i = t2 & 63;
      const float* x = &sUpd[item][s * 64];
      const float* h = &sSlots[item][s * 64];
      float gir = 0, giz = 0, gin = 0, ghr = 0, ghz = 0, ghn = 0;
      for (int j = 0; j < 64; j++) {
        float xv = x[j], hv = h[j];
        gir += xv * wihT[j * 192 + i];
        giz += xv * wihT[j * 192 + 64 + i];
        gin += xv * wihT[j * 192 + 128 + i];
        ghr += hv * whhT[j * 192 + i];
        ghz += hv * whhT[j * 192 + 64 + i];
        ghn += hv * whhT[j * 192 + 128 + i];
      }
      gir += bih[i]; giz += bih[64 + i]; gin += bih[128 + i];
      ghr += bhh[i]; ghz += bhh[64 + i]; ghn += bhh[128 + i];
      float r = fast_sigmoid(gir + ghr);
      float z = fast_sigmoid(giz + ghz);
      float nn = fast_tanh(gin + r * ghn);
      newslot = (1.f - z) * nn + z * h[i];
    }
    __syncthreads();
    sSlots[item][t2] = newslot;
    __syncthreads();
    {
      float x = sSlots[item][wv * 64 + ln];
      float m = wsumall(x) * (1.f / 64.f);
      float d0 = x - m;
      float var = wsumall(d0 * d0) * (1.f / 64.f);
      sNorm[item][wv * 64 + ln] = d0 * rsqrtf(var + LN_EPS) * lnff_w[ln] + lnff_b[ln];
    }
    __syncthreads();
    for (int o = t2; o < 1024; o += 512) {
      int s = o >> 7, k2 = o & 127;
      float acc = 0.f;
      for (int j = 0; j < 64; j++) acc += sNorm[item][s * 64 + j] * fc1T[j * 128 + k2];
      sHid[item][o] = fmaxf(acc + fc1_b[k2], 0.f);
    }
    __syncthreads();
    {
      int s = t2 >> 6, i = t2 & 63;
      float acc = 0.f;
      for (int j = 0; j < 128; j++) acc += sHid[item][s * 128 + j] * fc2T[j * 64 + i];
      newslot = sSlots[item][t2] + acc + fc2_b[i];
    }
    __syncthreads();
    sSlots[item][t2] = newslot;
    __syncthreads();
  }
  out[(long)b * 512 + t2] = sSlots[item][t2];
}

// ---------------------------------------------------------------------------
extern "C" void kernel_launch(void* const* d_in, const int* in_sizes, int n_in,
                              void* d_out, int out_size, void* d_ws, size_t ws_size,
                              hipStream_t stream) {
  (void)n_in; (void)out_size; (void)ws_size;
  char* ws = (char*)d_ws;
  float* cvt  = (float*)ws;                            // f32 inputs (4.7 MB)
  float* lgts = (float*)(ws + 5570560ull);             // RAW logits
  __hip_bfloat16* act1 = (__hip_bfloat16*)(ws + 5636096ull);   // bf16 33.55MB
  __hip_bfloat16* act2 = (__hip_bfloat16*)(ws + 39190528ull);  // bf16  8.39MB
  float* act3 = (float*)(ws + 5636096ull);             // over dead act1
  float* act4 = (float*)(ws + 9830400ull);             // live through token
  float* knT  = (float*)(ws + 14024704ull);            // 4 MB
  float* vf   = (float*)(ws + 18219008ull);            // 4 MB
  int*   flag = (int*)(ws + 47579136ull);
  float* tws  = (float*)(ws + 47583232ull);            // transposed weights

  CvtArgs ca;
  long total = 0;
  for (int i = 0; i < 39; i++) { ca.src[i] = d_in[i]; ca.off[i] = total; total += in_sizes[i]; }
  ca.off[39] = total;

  sniff_kernel<<<1, 64, 0, stream>>>((const unsigned int*)d_in[0], flag);
  convert_kernel<<<1024, 256, 0, stream>>>(ca, flag, cvt, total);

#define ARR(i) (cvt + ca.off[i])
  TwArgs ta;
  {
    const int src[9] = {12, 14, 18, 19, 20, 27, 28, 33, 35};
    const int R[9] = {64, 64, 64, 64, 64, 192, 192, 128, 64};
    const int C[9] = {64, 64, 64, 64, 64, 64, 64, 64, 128};
    long d = 0;
    for (int m2 = 0; m2 < 9; m2++) {
      ta.soff[m2] = ca.off[src[m2]];
      ta.doff[m2] = d;
      ta.R[m2] = R[m2];
      ta.C[m2] = C[m2];
      d += (long)R[m2] * C[m2];
    }
  }
  transw_kernel<<<9, 256, 0, stream>>>(cvt, tws, ta);
  float* mlp1T = tws + 0,     *mlp2T = tws + 4096,  *wkT = tws + 8192, *wvT = tws + 12288;
  float* wqT   = tws + 16384, *wihT  = tws + 20480, *whhT = tws + 32768;
  float* fc1T  = tws + 45056, *fc2T  = tws + 53248;

  const float* image = ARR(0);
  const float* noise = ARR(1);

  conv5x5<1, float, __hip_bfloat16><<<dim3(64, 4, 16), 256, 0, stream>>>(
      image, ARR(2), ARR(3), act1, 3, 128, 128, 128, 128, 64, 8);
  conv5x5<2, __hip_bfloat16, __hip_bfloat16><<<dim3(16, 4, 16), 256, 0, stream>>>(
      act1, ARR(4), ARR(5), act2, 64, 128, 128, 64, 64, 64, 4);
  conv5x5<2, __hip_bfloat16, float><<<dim3(4, 4, 16), 256, 0, stream>>>(
      act2, ARR(6), ARR(7), act3, 64, 64, 64, 32, 32, 64, 2);
  conv5x5<1, float, float><<<dim3(4, 4, 16), 256, 0, stream>>>(
      act3, ARR(8), ARR(9), act4, 64, 32, 32, 32, 32, 64, 2);

  token_kernel<<<16384, 64, 0, stream>>>(act4, ARR(10), ARR(11),
                                         mlp1T, ARR(13), mlp2T, ARR(15),
                                         ARR(16), ARR(17), wkT, wvT, ARR(21), ARR(22),
                                         knT, vf, lgts);

  sa_kernel<<<8, 1024, 0, stream>>>(knT, vf, lgts, noise, ARR(37), ARR(38),
                                    ARR(25), ARR(26), ARR(23), ARR(24), wqT,
                                    wihT, whhT, ARR(29), ARR(30),
                                    ARR(31), ARR(32), fc1T, ARR(34), fc2T, ARR(36),
                                    (float*)d_out);
#undef ARR
}

// Round 17
// 1238.102 us; speedup vs baseline: 1.7062x; 1.7062x over previous
//
#include <hip/hip_runtime.h>
#include <hip/hip_bf16.h>

// ---------------------------------------------------------------------------
// InvSlotAttentionGuide: CNN encoder -> pos embed -> MLP -> slot attention
// with MESH-Sinkhorn (manual reverse-mode through 5 sinkhorn iters).
// R17: exact revert to R13 (best measured: 1238 us). R16's 1024-thread
// 2-items/block packing halved the VGPR budget to 64 -> spilled the 26
// per-thread Sinkhorn state floats (FETCH/WRITE signature) -> 2112 us.
// CONSTRAINT (measured twice, R12+R16): sa needs 128 VGPR => 512 threads max.
// ---------------------------------------------------------------------------

#define LN_EPS 1e-5f
#define SEPS 1e-8f
#define LN8 2.0794415416798357f

__device__ inline float ldf(float x) { return x; }
__device__ inline float ldf(__hip_bfloat16 x) { return __bfloat162float(x); }
__device__ inline void stf(float* p, float v) { *p = v; }
__device__ inline void stf(__hip_bfloat16* p, float v) { *p = __float2bfloat16(v); }

__device__ inline float wmaxall(float v) {
#pragma unroll
  for (int o = 32; o; o >>= 1) v = fmaxf(v, __shfl_down(v, o));
  return __shfl(v, 0);
}
__device__ inline float wsumall(float v) {
#pragma unroll
  for (int o = 32; o; o >>= 1) v += __shfl_down(v, o);
  return __shfl(v, 0);
}
__device__ inline int wsumi(int v) {
#pragma unroll
  for (int o = 32; o; o >>= 1) v += __shfl_down(v, o);
  return __shfl(v, 0);
}
__device__ inline float fast_sigmoid(float x) { return 1.f / (1.f + __expf(-x)); }
__device__ inline float fast_tanh(float x) { return 1.f - 2.f / (__expf(2.f * x) + 1.f); }

// ---------------------------------------------------------------------------
__global__ __launch_bounds__(64) void sniff_kernel(const unsigned int* __restrict__ img,
                                                   int* __restrict__ flag) {
  int cnt = 0;
  for (int i = threadIdx.x; i < 512; i += 64) {
    unsigned lo = img[i] & 0xFFFFu;
    int e = (int)((lo >> 7) & 0xFFu);
    cnt += (e >= 96 && e <= 140) ? 1 : 0;
  }
  cnt = wsumi(cnt);
  if (threadIdx.x == 0) *flag = (cnt >= 300) ? 1 : 0;
}

struct CvtArgs {
  const void* src[39];
  long off[40];
};

__global__ __launch_bounds__(256) void convert_kernel(CvtArgs a, const int* __restrict__ flag,
                                                      float* __restrict__ dst, long total) {
  const int isbf = *flag;
  for (long g = (long)blockIdx.x * 256 + threadIdx.x; g < total; g += (long)gridDim.x * 256) {
    int lo = 0, hi = 38;
    while (lo < hi) {
      int mid = (lo + hi + 1) >> 1;
      if (a.off[mid] <= g) lo = mid; else hi = mid - 1;
    }
    long li = g - a.off[lo];
    float v;
    if (isbf) v = __bfloat162float(((const __hip_bfloat16*)a.src[lo])[li]);
    else      v = ((const float*)a.src[lo])[li];
    dst[g] = v;
  }
}

// ---------------------------------------------------------------------------
struct TwArgs {
  long soff[9]; long doff[9]; int R[9]; int C[9];
};

__global__ __launch_bounds__(256) void transw_kernel(const float* __restrict__ cvt,
                                                     float* __restrict__ tws, TwArgs a) {
  int m = blockIdx.x;
  const float* S = cvt + a.soff[m];
  float* D = tws + a.doff[m];
  int R = a.R[m], C = a.C[m];
  for (int idx = threadIdx.x; idx < R * C; idx += 256) {
    int i = idx / C, j = idx - i * C;
    D[j * R + i] = S[idx];
  }
}

// ---------------------------------------------------------------------------
// Direct 5x5 conv + bias + relu (R13-exact): 16x16 tile x 16 oc per block,
// float4 win loads from padded rows, wt[tap][16] broadcast b128.
// ---------------------------------------------------------------------------
template <int S, typename TIN, typename TOUT>
__global__ __launch_bounds__(256) void conv5x5(
    const TIN* __restrict__ in, const float* __restrict__ wgt,
    const float* __restrict__ bias, TOUT* __restrict__ out,
    int Cin, int H, int W, int Ho, int Wo, int Cout, int tilesX) {
  constexpr int P = 15 * S + 5;
  constexpr int PP = (S == 1) ? 20 : 36;
  constexpr int NCH = (S == 1) ? 2 : 3;
  __shared__ __align__(16) float patch[P * PP];
  __shared__ float wt16[25 * 16];
  const int b = blockIdx.z;
  const int ocg = blockIdx.y * 16;
  const int ty0 = (blockIdx.x / tilesX) * 16, tx0 = (blockIdx.x % tilesX) * 16;
  const int og = threadIdx.x >> 6;
  const int r = (threadIdx.x >> 2) & 15;
  const int rx = threadIdx.x & 3;
  const int iy0 = ty0 * S - 2, ix0 = tx0 * S - 2;
  float acc[4][4];
#pragma unroll
  for (int p = 0; p < 4; p++)
#pragma unroll
    for (int j = 0; j < 4; j++) acc[p][j] = 0.f;

  for (int ci = 0; ci < Cin; ++ci) {
    const TIN* inp = in + ((long)b * Cin + ci) * (long)H * W;
    for (int idx = threadIdx.x; idx < P * P; idx += 256) {
      int py = idx / P, px = idx - py * P;
      int iy = iy0 + py, ix = ix0 + px;
      float v = 0.f;
      if (iy >= 0 && iy < H && ix >= 0 && ix < W) v = ldf(inp[(long)iy * W + ix]);
      patch[py * PP + px] = v;
    }
    for (int idx = threadIdx.x; idx < 16 * 25; idx += 256) {
      int tap = idx >> 4, j = idx & 15;
      wt16[idx] = wgt[((long)(ocg + j) * Cin + ci) * 25 + tap];
    }
    __syncthreads();
#pragma unroll
    for (int ky = 0; ky < 5; ky++) {
      float win[4 * NCH];
      const float* bp = &patch[(r * S + ky) * PP + rx * 4 * S];
#pragma unroll
      for (int c = 0; c < NCH; c++) {
        float4 t4 = *(const float4*)(bp + 4 * c);
        win[4 * c + 0] = t4.x;
        win[4 * c + 1] = t4.y;
        win[4 * c + 2] = t4.z;
        win[4 * c + 3] = t4.w;
      }
#pragma unroll
      for (int kx = 0; kx < 5; kx++) {
        const float4 wv = *(const float4*)&wt16[(ky * 5 + kx) * 16 + og * 4];
#pragma unroll
        for (int p = 0; p < 4; p++) {
          float iv = win[p * S + kx];
          acc[p][0] += iv * wv.x;
          acc[p][1] += iv * wv.y;
          acc[p][2] += iv * wv.z;
          acc[p][3] += iv * wv.w;
        }
      }
    }
    __syncthreads();
  }
  const int oy = ty0 + r, ox0 = tx0 + rx * 4;
#pragma unroll
  for (int j = 0; j < 4; j++) {
    int oc = ocg + og * 4 + j;
    float bs = bias[oc];
    TOUT* op = &out[(((long)b * Cout + oc) * Ho + oy) * Wo + ox0];
#pragma unroll
    for (int p = 0; p < 4; p++) stf(&op[p], fmaxf(acc[p][j] + bs, 0.f));
  }
}

// ---------------------------------------------------------------------------
// Per-token (one wave): inline pos-embed from act4 -> MLP -> LN -> k
// (l2norm, stored TRANSPOSED [d][n]), v, mwi logit.  (R13-exact)
// ---------------------------------------------------------------------------
__global__ __launch_bounds__(64) void token_kernel(
    const float* __restrict__ act4, const float* __restrict__ pos_w,
    const float* __restrict__ pos_b,
    const float* __restrict__ mlp1T, const float* __restrict__ mlp1_b,
    const float* __restrict__ mlp2T, const float* __restrict__ mlp2_b,
    const float* __restrict__ lnin_w, const float* __restrict__ lnin_b,
    const float* __restrict__ wkT, const float* __restrict__ wvT,
    const float* __restrict__ mwi_w, const float* __restrict__ mwi_b,
    float* __restrict__ knT_out, float* __restrict__ v_out, float* __restrict__ lg_out) {
  const int t = blockIdx.x, i = threadIdx.x;
  const int b = t >> 10, nn = t & 1023;
  const int h = nn >> 5, w = nn & 31;
  __shared__ float f[64], h1[64], inp[64];
  {
    float gh = h * (1.f / 31.f), gw = w * (1.f / 31.f);
    float e = gh * pos_w[i * 4 + 0] + gw * pos_w[i * 4 + 1] +
              (1.f - gh) * pos_w[i * 4 + 2] + (1.f - gw) * pos_w[i * 4 + 3] + pos_b[i];
    f[i] = act4[(((long)b * 64 + i) * 32 + h) * 32 + w] + e;
  }
  __syncthreads();
  float acc = 0.f;
  for (int j = 0; j < 64; j++) acc += f[j] * mlp1T[j * 64 + i];
  h1[i] = fmaxf(acc + mlp1_b[i], 0.f);
  __syncthreads();
  acc = 0.f;
  for (int j = 0; j < 64; j++) acc += h1[j] * mlp2T[j * 64 + i];
  float x = acc + mlp2_b[i];
  float m = wsumall(x) * (1.f / 64.f);
  float d0 = x - m;
  float var = wsumall(d0 * d0) * (1.f / 64.f);
  float xin = d0 * rsqrtf(var + LN_EPS) * lnin_w[i] + lnin_b[i];
  inp[i] = xin;
  __syncthreads();
  float kv = 0.f, vv = 0.f;
  for (int j = 0; j < 64; j++) {
    float ij = inp[j];
    kv += ij * wkT[j * 64 + i];
    vv += ij * wvT[j * 64 + i];
  }
  float ss = wsumall(kv * kv);
  knT_out[(long)b * 65536 + i * 1024 + nn] = kv / fmaxf(sqrtf(ss), 1e-12f);
  v_out[(long)t * 64 + i] = vv;
  float lg = wsumall(xin * mwi_w[i]);
  if (i == 0) lg_out[t] = lg + mwi_b[0];
}

// ---------------------------------------------------------------------------
// Slot-attention loop (R13-exact): 512 threads = 8 waves, LSE-reuse fused
// backward + max-free column LSEs. 128 VGPR — do not exceed 512 threads.
// ---------------------------------------------------------------------------
__global__ __launch_bounds__(512) void sa_kernel(
    const float* __restrict__ knT_g, const float* __restrict__ v_g,
    const float* __restrict__ la_g, const float* __restrict__ noise,
    const float* __restrict__ mu_w, const float* __restrict__ sg_w,
    const float* __restrict__ lnsl_w, const float* __restrict__ lnsl_b,
    const float* __restrict__ mws_w, const float* __restrict__ mws_b,
    const float* __restrict__ wqT,
    const float* __restrict__ wihT, const float* __restrict__ whhT,
    const float* __restrict__ bih, const float* __restrict__ bhh,
    const float* __restrict__ lnff_w, const float* __restrict__ lnff_b,
    const float* __restrict__ fc1T, const float* __restrict__ fc1_b,
    const float* __restrict__ fc2T, const float* __restrict__ fc2_b,
    float* __restrict__ out) {
  const int b = blockIdx.x, tid = threadIdx.x;
  const int wv = tid >> 6, ln = tid & 63;

  __shared__ float sCt[8192];
  __shared__ float sLa[1024], sU[1024], sGu[1024], sRow[1024], sHid[1024];
  __shared__ float sVh[48], sV[8], sGv[8], sLb[8], sBm[8];
  __shared__ float sLaMax;
  __shared__ float sSlots[512], sNorm[512], sQn[512], sUpd[512];

  const float* knt = knT_g + (long)b * 65536;
  const float* vf = v_g + (long)b * 65536;
  float u_hist[5][2];
  float gPr[2][8];
  float gInit[2];

  {
    int dd = tid & 63;
    sSlots[tid] = mu_w[dd] + (fabsf(sg_w[dd]) + SEPS) * noise[(long)b * 512 + tid];
  }
  for (int n = tid; n < 1024; n += 512) sLa[n] = la_g[b * 1024 + n];
  __syncthreads();
  {  // fused la: sLa <- raw - LSE + ln8 ; record laMax
    float a0 = sLa[tid], a1 = sLa[tid + 512];
    float m0 = wmaxall(fmaxf(a0, a1));
    if (ln == 0) sBm[wv] = m0;
    __syncthreads();
    float M = sBm[0];
#pragma unroll
    for (int s = 1; s < 8; s++) M = fmaxf(M, sBm[s]);
    float e0 = wsumall(__expf(a0 - M) + __expf(a1 - M));
    if (ln == 0) sGv[wv] = e0;
    __syncthreads();
    float SS = 0.f;
#pragma unroll
    for (int s = 0; s < 8; s++) SS += sGv[s];
    float lse = M + __logf(SS);
    sLa[tid] = a0 - lse + LN8;
    sLa[tid + 512] = a1 - lse + LN8;
    if (tid == 0) sLaMax = M - lse + LN8;
  }
  __syncthreads();
  const float laMax = sLaMax;

  for (int it = 0; it < 3; ++it) {
    {
      float x = sSlots[wv * 64 + ln];
      float m = wsumall(x) * (1.f / 64.f);
      float d0 = x - m;
      float var = wsumall(d0 * d0) * (1.f / 64.f);
      float xn = d0 * rsqrtf(var + LN_EPS) * lnsl_w[ln] + lnsl_b[ln];
      sNorm[wv * 64 + ln] = xn;
      float bmv = wsumall(xn * mws_w[ln]);
      if (ln == 0) sBm[wv] = bmv + mws_b[0];
    }
    __syncthreads();
    if (tid == 0) {
      float mx = -1e30f;
      for (int s = 0; s < 8; s++) mx = fmaxf(mx, sBm[s]);
      float ss = 0.f;
      for (int s = 0; s < 8; s++) ss += __expf(sBm[s] - mx);
      float lse = mx + __logf(ss);
      for (int s = 0; s < 8; s++) sLb[s] = sBm[s] - lse + LN8;
    }
    {
      float acc = 0.f;
      for (int j = 0; j < 64; j++) acc += sNorm[wv * 64 + j] * wqT[j * 64 + ln];
      sQn[tid] = acc;
    }
    __syncthreads();
    {
      float qv = sQn[wv * 64 + ln];
      float ss = wsumall(qv * qv);
      sQn[wv * 64 + ln] = qv / fmaxf(sqrtf(ss), 1e-12f);
    }
    if (tid < 8) sV[tid] = 0.f;
    __syncthreads();

#pragma unroll
    for (int k = 0; k < 2; k++) {
      int n = tid + 512 * k;
      float acc[8];
#pragma unroll
      for (int s = 0; s < 8; s++) acc[s] = 0.f;
      for (int j = 0; j < 64; j++) {
        float kvv = knt[j * 1024 + n];
#pragma unroll
        for (int s = 0; s < 8; s++) acc[s] += kvv * sQn[s * 64 + j];
      }
#pragma unroll
      for (int s = 0; s < 8; s++) sCt[s * 1024 + n] = 1.f - acc[s];
    }
    __syncthreads();

    for (int m = 0; m < 4; m++) {
#pragma unroll
      for (int t = 1; t <= 5; t++) {
        if (t == 1 && tid < 8) sVh[tid] = sV[tid];
#pragma unroll
        for (int k = 0; k < 2; k++) {
          int n = tid + 512 * k;
          float mx = -1e30f;
#pragma unroll
          for (int s = 0; s < 8; s++) mx = fmaxf(mx, sV[s] - sCt[s * 1024 + n]);
          float ssum = 0.f;
#pragma unroll
          for (int s = 0; s < 8; s++) ssum += __expf(sV[s] - sCt[s * 1024 + n] - mx);
          float un = sLa[n] - (mx + __logf(ssum));
          sU[n] = un;
          u_hist[t - 1][k] = un;
        }
        __syncthreads();
        {
          int s = wv;
          float ms = laMax - sV[s];
          float ssum = 0.f;
          for (int n = ln; n < 1024; n += 64)
            ssum += __expf(sU[n] - sCt[s * 1024 + n] - ms);
          ssum = wsumall(ssum);
          if (ln == 0) {
            float vs = sLb[s] - (ms + __logf(ssum));
            sV[s] = vs;
            sVh[t * 8 + s] = vs;
          }
        }
        __syncthreads();
      }
      {
#pragma unroll
        for (int k = 0; k < 2; k++) {
          int n = tid + 512 * k;
          float un = u_hist[4][k];
          float gul = 0.f;
#pragma unroll
          for (int s = 0; s < 8; s++) {
            float pi = __expf(un + sV[s] - sCt[s * 1024 + n]);
            float gl = -(__logf(pi + SEPS) + pi / (pi + SEPS)) * pi * (1.f / 16.f);
            gPr[k][s] = gl;
            gul += gl;
          }
          gInit[k] = gul;
        }
        {
          int s = wv;
          float vs = sV[s];
          float acc = 0.f;
          for (int n = ln; n < 1024; n += 64) {
            float pi = __expf(sU[n] + vs - sCt[s * 1024 + n]);
            acc += -(__logf(pi + SEPS) + pi / (pi + SEPS)) * pi * (1.f / 16.f);
          }
          acc = wsumall(acc);
          if (ln == 0) sGv[s] = acc;
        }
      }
      __syncthreads();
#pragma unroll
      for (int t = 5; t >= 1; t--) {
        {
#pragma unroll
          for (int k = 0; k < 2; k++) {
            int n = tid + 512 * k;
            float un = u_hist[t - 1][k];
            float gul = (t == 5) ? gInit[k] : 0.f;
#pragma unroll
            for (int s = 0; s < 8; s++) {
              float t2 = sGv[s] * __expf(un - sCt[s * 1024 + n] - (sLb[s] - sVh[t * 8 + s]));
              gPr[k][s] -= t2;
              gul -= t2;
            }
            float rowlse = sLa[n] - un;
#pragma unroll
            for (int s = 0; s < 8; s++)
              gPr[k][s] -= gul * __expf(sVh[(t - 1) * 8 + s] - sCt[s * 1024 + n] - rowlse);
            sGu[n] = gul;
            sRow[n] = rowlse;
            if (t == 1) {
#pragma unroll
              for (int s = 0; s < 8; s++) sCt[s * 1024 + n] += gPr[k][s];
            }
          }
          if (t == 1 && tid < 8) sV[tid] = sVh[40 + tid];
        }
        __syncthreads();
        if (t > 1) {
          int s = wv;
          float vvh = sVh[(t - 1) * 8 + s];
          float acc = 0.f;
          for (int n = ln; n < 1024; n += 64)
            acc += sGu[n] * __expf(vvh - sCt[s * 1024 + n] - sRow[n]);
          acc = wsumall(acc);
          if (ln == 0) sGv[s] = -acc;
          __syncthreads();
        }
      }
    }

    for (int t = 0; t < 5; t++) {
#pragma unroll
      for (int k = 0; k < 2; k++) {
        int n = tid + 512 * k;
        float mx = -1e30f;
#pragma unroll
        for (int s = 0; s < 8; s++) mx = fmaxf(mx, sV[s] - sCt[s * 1024 + n]);
        float ssum = 0.f;
#pragma unroll
        for (int s = 0; s < 8; s++) ssum += __expf(sV[s] - sCt[s * 1024 + n] - mx);
        sU[n] = sLa[n] - (mx + __logf(ssum));
      }
      __syncthreads();
      {
        int s = wv;
        float ms = laMax - sV[s];
        float ssum = 0.f;
        for (int n = ln; n < 1024; n += 64)
          ssum += __expf(sU[n] - sCt[s * 1024 + n] - ms);
        ssum = wsumall(ssum);
        if (ln == 0) sV[s] = sLb[s] - (ms + __logf(ssum));
      }
      __syncthreads();
    }
#pragma unroll
    for (int k = 0; k < 2; k++) {
      int n = tid + 512 * k;
      float un = sU[n];
#pragma unroll
      for (int s = 0; s < 8; s++) sCt[s * 1024 + n] = __expf(un + sV[s] - sCt[s * 1024 + n]);
    }
    __syncthreads();
    if (it == 2) {
      for (int o = tid; o < 8192; o += 512) out[8192 + (long)b * 8192 + o] = sCt[o];
    }
    {
      int s = tid >> 6, dd = tid & 63;
      float acc = 0.f;
      for (int n = 0; n < 1024; n++) acc += sCt[s * 1024 + n] * vf[n * 64 + dd];
      sUpd[tid] = acc;
    }
    __syncthreads();
    float newslot;
    {
      int s = tid >> 6, i = tid & 63;
      const float* x = &sUpd[s * 64];
      const float* h = &sSlots[s * 64];
      float gir = 0, giz = 0, gin = 0, ghr = 0, ghz = 0, ghn = 0;
      for (int j = 0; j < 64; j++) {
        float xv = x[j], hv = h[j];
        gir += xv * wihT[j * 192 + i];
        giz += xv * wihT[j * 192 + 64 + i];
        gin += xv * wihT[j * 192 + 128 + i];
        ghr += hv * whhT[j * 192 + i];
        ghz += hv * whhT[j * 192 + 64 + i];
        ghn += hv * whhT[j * 192 + 128 + i];
      }
      gir += bih[i]; giz += bih[64 + i]; gin += bih[128 + i];
      ghr += bhh[i]; ghz += bhh[64 + i]; ghn += bhh[128 + i];
      float r = fast_sigmoid(gir + ghr);
      float z = fast_sigmoid(giz + ghz);
      float nn = fast_tanh(gin + r * ghn);
      newslot = (1.f - z) * nn + z * h[i];
    }
    __syncthreads();
    sSlots[tid] = newslot;
    __syncthreads();
    {
      float x = sSlots[wv * 64 + ln];
      float m = wsumall(x) * (1.f / 64.f);
      float d0 = x - m;
      float var = wsumall(d0 * d0) * (1.f / 64.f);
      sNorm[wv * 64 + ln] = d0 * rsqrtf(var + LN_EPS) * lnff_w[ln] + lnff_b[ln];
    }
    __syncthreads();
    for (int o = tid; o < 1024; o += 512) {
      int s = o >> 7, k2 = o & 127;
      float acc = 0.f;
      for (int j = 0; j < 64; j++) acc += sNorm[s * 64 + j] * fc1T[j * 128 + k2];
      sHid[o] = fmaxf(acc + fc1_b[k2], 0.f);
    }
    __syncthreads();
    {
      int s = tid >> 6, i = tid & 63;
      float acc = 0.f;
      for (int j = 0; j < 128; j++) acc += sHid[s * 128 + j] * fc2T[j * 64 + i];
      newslot = sSlots[tid] + acc + fc2_b[i];
    }
    __syncthreads();
    sSlots[tid] = newslot;
    __syncthreads();
  }
  out[(long)b * 512 + tid] = sSlots[tid];
}

// ---------------------------------------------------------------------------
extern "C" void kernel_launch(void* const* d_in, const int* in_sizes, int n_in,
                              void* d_out, int out_size, void* d_ws, size_t ws_size,
                              hipStream_t stream) {
  (void)n_in; (void)out_size; (void)ws_size;
  char* ws = (char*)d_ws;
  float* cvt  = (float*)ws;                            // f32 inputs (4.7 MB)
  float* lgts = (float*)(ws + 5570560ull);             // RAW logits
  __hip_bfloat16* act1 = (__hip_bfloat16*)(ws + 5636096ull);   // bf16 33.55MB
  __hip_bfloat16* act2 = (__hip_bfloat16*)(ws + 39190528ull);  // bf16  8.39MB
  float* act3 = (float*)(ws + 5636096ull);             // over dead act1
  float* act4 = (float*)(ws + 9830400ull);             // live through token
  float* knT  = (float*)(ws + 14024704ull);            // 4 MB
  float* vf   = (float*)(ws + 18219008ull);            // 4 MB
  int*   flag = (int*)(ws + 47579136ull);
  float* tws  = (float*)(ws + 47583232ull);            // transposed weights

  CvtArgs ca;
  long total = 0;
  for (int i = 0; i < 39; i++) { ca.src[i] = d_in[i]; ca.off[i] = total; total += in_sizes[i]; }
  ca.off[39] = total;

  sniff_kernel<<<1, 64, 0, stream>>>((const unsigned int*)d_in[0], flag);
  convert_kernel<<<1024, 256, 0, stream>>>(ca, flag, cvt, total);

#define ARR(i) (cvt + ca.off[i])
  TwArgs ta;
  {
    const int src[9] = {12, 14, 18, 19, 20, 27, 28, 33, 35};
    const int R[9] = {64, 64, 64, 64, 64, 192, 192, 128, 64};
    const int C[9] = {64, 64, 64, 64, 64, 64, 64, 64, 128};
    long d = 0;
    for (int m2 = 0; m2 < 9; m2++) {
      ta.soff[m2] = ca.off[src[m2]];
      ta.doff[m2] = d;
      ta.R[m2] = R[m2];
      ta.C[m2] = C[m2];
      d += (long)R[m2] * C[m2];
    }
  }
  transw_kernel<<<9, 256, 0, stream>>>(cvt, tws, ta);
  float* mlp1T = tws + 0,     *mlp2T = tws + 4096,  *wkT = tws + 8192, *wvT = tws + 12288;
  float* wqT   = tws + 16384, *wihT  = tws + 20480, *whhT = tws + 32768;
  float* fc1T  = tws + 45056, *fc2T  = tws + 53248;

  const float* image = ARR(0);
  const float* noise = ARR(1);

  conv5x5<1, float, __hip_bfloat16><<<dim3(64, 4, 16), 256, 0, stream>>>(
      image, ARR(2), ARR(3), act1, 3, 128, 128, 128, 128, 64, 8);
  conv5x5<2, __hip_bfloat16, __hip_bfloat16><<<dim3(16, 4, 16), 256, 0, stream>>>(
      act1, ARR(4), ARR(5), act2, 64, 128, 128, 64, 64, 64, 4);
  conv5x5<2, __hip_bfloat16, float><<<dim3(4, 4, 16), 256, 0, stream>>>(
      act2, ARR(6), ARR(7), act3, 64, 64, 64, 32, 32, 64, 2);
  conv5x5<1, float, float><<<dim3(4, 4, 16), 256, 0, stream>>>(
      act3, ARR(8), ARR(9), act4, 64, 32, 32, 32, 32, 64, 2);

  token_kernel<<<16384, 64, 0, stream>>>(act4, ARR(10), ARR(11),
                                         mlp1T, ARR(13), mlp2T, ARR(15),
                                         ARR(16), ARR(17), wkT, wvT, ARR(21), ARR(22),
                                         knT, vf, lgts);

  sa_kernel<<<16, 512, 0, stream>>>(knT, vf, lgts, noise, ARR(37), ARR(38),
                                    ARR(25), ARR(26), ARR(23), ARR(24), wqT,
                                    wihT, whhT, ARR(29), ARR(30),
                                    ARR(31), ARR(32), fc1T, ARR(34), fc2T, ARR(36),
                                    (float*)d_out);
#undef ARR
}